// Round 1
// baseline (362.749 us; speedup 1.0000x reference)
//
#include <hip/hip_runtime.h>
#include <hip/hip_bf16.h>
#include <cstdint>
#include <cstddef>

// TripletLoss: inputs (8192,128) fp32, targets (8192,) int32, 64 classes.
// out[0] = loss, out[1..] = dist (8192x8192) row-major fp32.
// Strategy: bf16 MFMA GEMM for x@x^T (write-bound kernel, ~43us HBM floor for
// the 268MB dist write), fused per-row hard-pos/hard-neg reduction via
// in-register shuffle + global int atomics, tiny final loss kernel.

#define NROWS 8192
#define DIMK  128
#define MARGIN 0.3f

typedef __bf16 bf16x8 __attribute__((ext_vector_type(8)));
typedef float  f32x4  __attribute__((ext_vector_type(4)));
typedef int    i32x4  __attribute__((ext_vector_type(4)));
typedef float  f32x2  __attribute__((ext_vector_type(2)));

__device__ __forceinline__ unsigned short f2bf(float f) {
    // round-to-nearest-even fp32 -> bf16
    unsigned u = __float_as_uint(f);
    u += 0x7fffu + ((u >> 16) & 1u);
    return (unsigned short)(u >> 16);
}

// prep: convert X to bf16 (RNE) into ws, compute row sq-norms FROM THE
// ROUNDED VALUES (fp32 accumulate; keeps sqd self-consistent so the
// diagonal lands near 0), and init the ap/an reduction arrays.
// grid: 2048 x 256 (one wave per row; first 8192 threads also do init).
__global__ __launch_bounds__(256) void prep_kernel(
    const float* __restrict__ X, unsigned short* __restrict__ Xb,
    float* __restrict__ sq, int* __restrict__ ap, int* __restrict__ an)
{
    const int t = blockIdx.x * 256 + threadIdx.x;
    if (t < NROWS) { ap[t] = 0; an[t] = 0x7f800000; }  // 0.0f / +inf
    const int row  = t >> 6;
    const int lane = t & 63;
    const f32x2 v = *(const f32x2*)(X + (size_t)row * DIMK + lane * 2);
    const unsigned short b0 = f2bf(v[0]);
    const unsigned short b1 = f2bf(v[1]);
    *(unsigned*)(Xb + (size_t)row * DIMK + lane * 2) =
        (unsigned)b0 | ((unsigned)b1 << 16);
    const float f0 = __uint_as_float((unsigned)b0 << 16);
    const float f1 = __uint_as_float((unsigned)b1 << 16);
    float s = f0 * f0 + f1 * f1;
    #pragma unroll
    for (int off = 32; off; off >>= 1) s += __shfl_xor(s, off);
    if (lane == 0) sq[row] = s;
}

// dist kernel: 128x128 output tile per block (grid 64x64), 256 threads =
// 4 waves, each wave a 64x64 subtile via 4x4 grid of 16x16x32 bf16 MFMA.
// K=128 staged entirely once via global_load_lds width=16 (64 KB LDS ->
// 2 blocks/CU; fine, kernel is HBM-write-bound).
__global__ __launch_bounds__(256, 2) void dist_kernel(
    const unsigned short* __restrict__ Xb, const float* __restrict__ sq,
    const int* __restrict__ tgt, float* __restrict__ dist,
    int* __restrict__ ap, int* __restrict__ an)
{
    __shared__ unsigned short As[128 * DIMK];  // [row][k], 32 KB
    __shared__ unsigned short Bs[128 * DIMK];  // [col][k], 32 KB

    const int t  = threadIdx.x;
    const int bm = blockIdx.x, bn = blockIdx.y;

    // ---- stage A and B tiles (each: 128 rows x 256B, contiguous) ----
    {
        const char* gA = (const char*)Xb + (size_t)bm * (128 * DIMK * 2);
        const char* gB = (const char*)Xb + (size_t)bn * (128 * DIMK * 2);
        #pragma unroll
        for (int i = 0; i < 8; i++) {
            const int off = i * 4096 + t * 16;
            __builtin_amdgcn_global_load_lds(
                (const __attribute__((address_space(1))) void*)(gA + off),
                (__attribute__((address_space(3))) void*)((char*)As + off),
                16, 0, 0);
        }
        #pragma unroll
        for (int i = 0; i < 8; i++) {
            const int off = i * 4096 + t * 16;
            __builtin_amdgcn_global_load_lds(
                (const __attribute__((address_space(1))) void*)(gB + off),
                (__attribute__((address_space(3))) void*)((char*)Bs + off),
                16, 0, 0);
        }
    }
    __syncthreads();

    const int lane = t & 63, wave = t >> 6;
    const int wm = (wave >> 1) * 64, wn = (wave & 1) * 64;
    const int l15 = lane & 15, quad = lane >> 4;

    f32x4 acc[4][4];
    #pragma unroll
    for (int mi = 0; mi < 4; mi++)
        #pragma unroll
        for (int ni = 0; ni < 4; ni++)
            acc[mi][ni] = (f32x4){0.f, 0.f, 0.f, 0.f};

    // ---- MFMA K loop: 4 k-steps of 32 ----
    #pragma unroll
    for (int ks = 0; ks < 4; ks++) {
        const int kb = ks * 32 + quad * 8;  // A/B operand: k = quad*8 + j
        bf16x8 a_frag[4], b_frag[4];
        #pragma unroll
        for (int mi = 0; mi < 4; mi++)
            a_frag[mi] = *(const bf16x8*)(As + (wm + mi * 16 + l15) * DIMK + kb);
        #pragma unroll
        for (int ni = 0; ni < 4; ni++)
            b_frag[ni] = *(const bf16x8*)(Bs + (wn + ni * 16 + l15) * DIMK + kb);
        #pragma unroll
        for (int mi = 0; mi < 4; mi++)
            #pragma unroll
            for (int ni = 0; ni < 4; ni++)
                acc[mi][ni] = __builtin_amdgcn_mfma_f32_16x16x32_bf16(
                    a_frag[mi], b_frag[ni], acc[mi][ni], 0, 0, 0);
    }

    // ---- epilogue: sqd -> dist, store, fused per-row max/min ----
    // C/D layout: col = lane&15, row = quad*4 + reg (per frag).
    const int rbase = bm * 128 + wm;
    const int cbase = bn * 128 + wn;
    const float INF = __int_as_float(0x7f800000);

    float sqc[4]; int tc[4]; int cg[4];
    #pragma unroll
    for (int ni = 0; ni < 4; ni++) {
        cg[ni]  = cbase + ni * 16 + l15;
        sqc[ni] = sq[cg[ni]];
        tc[ni]  = tgt[cg[ni]];
    }

    #pragma unroll
    for (int mi = 0; mi < 4; mi++) {
        const int rg0 = rbase + mi * 16 + quad * 4;      // 16B aligned
        const f32x4 sqr = *(const f32x4*)(sq + rg0);
        const i32x4 tr  = *(const i32x4*)(tgt + rg0);
        #pragma unroll
        for (int reg = 0; reg < 4; reg++) {
            const int rg = rg0 + reg;
            float apv = -1.0f, anv = INF;
            #pragma unroll
            for (int ni = 0; ni < 4; ni++) {
                const float dot = acc[mi][ni][reg];
                float sqd = sqr[reg] + sqc[ni] - 2.0f * dot;
                float d = sqd > 0.0f ? sqrtf(sqd) : 0.0f;
                if (rg == cg[ni]) d = 0.0f;              // exact diagonal
                __builtin_nontemporal_store(d, dist + (size_t)rg * NROWS + cg[ni]);
                const bool same = (tr[reg] == tc[ni]);
                apv = fmaxf(apv, same ? d : -1.0f);
                anv = fminf(anv, same ? INF : d);
            }
            // reduce across the 16 lanes of this quad group (cols)
            #pragma unroll
            for (int m = 1; m < 16; m <<= 1) {
                apv = fmaxf(apv, __shfl_xor(apv, m));
                anv = fminf(anv, __shfl_xor(anv, m));
            }
            // one lane per row commits; int compare == float compare for >=0
            if (l15 == mi * 4 + reg) {
                atomicMax(ap + rg, __float_as_int(apv));
                atomicMin(an + rg, __float_as_int(anv));
            }
        }
    }
}

__global__ __launch_bounds__(256) void loss_kernel(
    const int* __restrict__ ap, const int* __restrict__ an,
    float* __restrict__ out)
{
    __shared__ float red[4];
    float s = 0.0f;
    for (int i = threadIdx.x; i < NROWS; i += 256) {
        const float v = __int_as_float(ap[i]) - __int_as_float(an[i]) + MARGIN;
        s += v > 0.0f ? v : 0.0f;
    }
    #pragma unroll
    for (int off = 32; off; off >>= 1) s += __shfl_xor(s, off);
    if ((threadIdx.x & 63) == 0) red[threadIdx.x >> 6] = s;
    __syncthreads();
    if (threadIdx.x == 0)
        out[0] = (red[0] + red[1] + red[2] + red[3]) * (1.0f / NROWS);
}

extern "C" void kernel_launch(void* const* d_in, const int* in_sizes, int n_in,
                              void* d_out, int out_size, void* d_ws, size_t ws_size,
                              hipStream_t stream)
{
    const float* X   = (const float*)d_in[0];
    const int*   tgt = (const int*)d_in[1];
    float*       out = (float*)d_out;

    // ws layout: Xb bf16 8192x128 (2 MB) | sq (32 KB) | ap (32 KB) | an (32 KB)
    unsigned short* Xb = (unsigned short*)d_ws;
    float* sq = (float*)((char*)d_ws + (size_t)NROWS * DIMK * 2);
    int*   ap = (int*)(sq + NROWS);
    int*   an = ap + NROWS;

    prep_kernel<<<(NROWS * 64) / 256, 256, 0, stream>>>(X, Xb, sq, ap, an);

    dim3 grid(64, 64);
    dist_kernel<<<grid, 256, 0, stream>>>(Xb, sq, tgt, out + 1, ap, an);

    loss_kernel<<<1, 256, 0, stream>>>(ap, an, out);
}